// Round 1
// baseline (591.759 us; speedup 1.0000x reference)
//
#include <hip/hip_runtime.h>
#include <hip/hip_bf16.h>
#include <stdint.h>

#define BB 4
#define SS 2048
#define DD 1024
#define HH 16
#define DHH 64

typedef __attribute__((ext_vector_type(8))) short short8_t;
typedef __attribute__((ext_vector_type(4))) float f32x4;
typedef unsigned short u16;

static __device__ __forceinline__ u16 f2bf(float x) {
    uint32_t u = __float_as_uint(x);
    u += 0x7fffu + ((u >> 16) & 1u);
    return (u16)(u >> 16);
}

// ---------------------------------------------------------------------------
// Fused QKV projection: out = X @ W^T + b, stored bf16 as [B,H,S,DH]
// 128x128 tile, BK=32, 256 threads (4 waves, 2x2), mfma 16x16x32 bf16.
// ---------------------------------------------------------------------------
__global__ __launch_bounds__(256) void qkv_gemm(
    const float* __restrict__ Xq, const float* __restrict__ Xk, const float* __restrict__ Xv,
    const float* __restrict__ Wq, const float* __restrict__ Wk, const float* __restrict__ Wv,
    const float* __restrict__ bq, const float* __restrict__ bk, const float* __restrict__ bv,
    u16* __restrict__ oq, u16* __restrict__ ok, u16* __restrict__ ov)
{
    const float* X; const float* W; const float* bias; u16* out;
    if (blockIdx.z == 0)      { X = Xq; W = Wq; bias = bq; out = oq; }
    else if (blockIdx.z == 1) { X = Xk; W = Wk; bias = bk; out = ok; }
    else                      { X = Xv; W = Wv; bias = bv; out = ov; }

    __shared__ u16 As[128][40];
    __shared__ u16 Bs[128][40];

    const int tid = threadIdx.x;
    const int lane = tid & 63;
    const int w  = tid >> 6;
    const int wr = w >> 1, wc = w & 1;
    const int g  = lane >> 4, c = lane & 15;

    const int m0 = blockIdx.x * 128;
    const int n0 = blockIdx.y * 128;

    f32x4 acc[4][4] = {};

    const int sr = tid >> 1;
    const int sc = (tid & 1) * 16;

    const float* ap = X + (size_t)(m0 + sr) * DD + sc;
    const float* bp = W + (size_t)(n0 + sr) * DD + sc;

    for (int k0 = 0; k0 < DD; k0 += 32) {
        f32x4 a4[4], b4[4];
#pragma unroll
        for (int i = 0; i < 4; i++) a4[i] = *(const f32x4*)(ap + k0 + i * 4);
#pragma unroll
        for (int i = 0; i < 4; i++) b4[i] = *(const f32x4*)(bp + k0 + i * 4);
        short8_t wa0, wa1, wb0, wb1;
#pragma unroll
        for (int j = 0; j < 8; j++) {
            wa0[j] = (short)f2bf(a4[j >> 2][j & 3]);
            wa1[j] = (short)f2bf(a4[2 + (j >> 2)][j & 3]);
            wb0[j] = (short)f2bf(b4[j >> 2][j & 3]);
            wb1[j] = (short)f2bf(b4[2 + (j >> 2)][j & 3]);
        }
        __syncthreads();
        *(short8_t*)&As[sr][sc]     = wa0;
        *(short8_t*)&As[sr][sc + 8] = wa1;
        *(short8_t*)&Bs[sr][sc]     = wb0;
        *(short8_t*)&Bs[sr][sc + 8] = wb1;
        __syncthreads();

        short8_t af[4], bf_[4];
#pragma unroll
        for (int m = 0; m < 4; m++) af[m]  = *(const short8_t*)&As[wr * 64 + m * 16 + c][g * 8];
#pragma unroll
        for (int n = 0; n < 4; n++) bf_[n] = *(const short8_t*)&Bs[wc * 64 + n * 16 + c][g * 8];
#pragma unroll
        for (int m = 0; m < 4; m++)
#pragma unroll
            for (int n = 0; n < 4; n++)
                acc[m][n] = __builtin_amdgcn_mfma_f32_16x16x32_bf16(af[m], bf_[n], acc[m][n], 0, 0, 0);
    }

#pragma unroll
    for (int m = 0; m < 4; m++) {
#pragma unroll
        for (int n = 0; n < 4; n++) {
            const int gn = n0 + wc * 64 + n * 16 + c;
            const int h = gn >> 6, dh = gn & 63;
            const float bv_ = bias[gn];
#pragma unroll
            for (int i = 0; i < 4; i++) {
                const int gm = m0 + wr * 64 + m * 16 + g * 4 + i;
                const int b = gm >> 11, s = gm & (SS - 1);
                out[(((size_t)(b * HH + h)) * SS + s) * DHH + dh] = f2bf(acc[m][n][i] + bv_);
            }
        }
    }
}

// ---------------------------------------------------------------------------
// Flash-style causal attention. Block = (q-tile of 64 rows) x (b,h).
// 4 waves, each owns 16 q-rows. K/V staged per 64-key tile; V transposed.
// ---------------------------------------------------------------------------
__global__ __launch_bounds__(256) void attn_kernel(
    const u16* __restrict__ qb, const u16* __restrict__ kb,
    const u16* __restrict__ vb, u16* __restrict__ attb)
{
    __shared__ u16 Kt[64][72];      // Kt[key][dh]
    __shared__ u16 Vt[64][72];      // Vt[dh][key]
    __shared__ u16 Pb[4][16][72];   // per-wave P tile [qrow][key]

    const int tid = threadIdx.x;
    const int lane = tid & 63;
    const int w = tid >> 6;
    const int qt = blockIdx.x;
    const int bh = blockIdx.y;
    const size_t base = (size_t)bh * SS * DHH;

    const int g = lane >> 4;   // 0..3
    const int c = lane & 15;   // 0..15

    const int q0 = qt * 64 + w * 16;

    short8_t qa[2];
#pragma unroll
    for (int kc = 0; kc < 2; kc++)
        qa[kc] = *(const short8_t*)(qb + base + (size_t)(q0 + c) * DHH + kc * 32 + g * 8);

    f32x4 o[4] = {};
    float mrow[4], lrow[4];
#pragma unroll
    for (int i = 0; i < 4; i++) { mrow[i] = -1e30f; lrow[i] = 0.f; }

    const int sr  = tid >> 2;        // 0..63
    const int scc = (tid & 3) * 16;  // 0,16,32,48

    for (int t = 0; t <= qt; t++) {
        __syncthreads();
        {
            const u16* kp = kb + base + (size_t)(t * 64 + sr) * DHH + scc;
            short8_t k0v = *(const short8_t*)kp;
            short8_t k1v = *(const short8_t*)(kp + 8);
            *(short8_t*)&Kt[sr][scc]     = k0v;
            *(short8_t*)&Kt[sr][scc + 8] = k1v;
            const u16* vp = vb + base + (size_t)(t * 64 + sr) * DHH + scc;
            short8_t v0v = *(const short8_t*)vp;
            short8_t v1v = *(const short8_t*)(vp + 8);
#pragma unroll
            for (int j = 0; j < 8; j++) {
                Vt[scc + j][sr]     = (u16)v0v[j];
                Vt[scc + 8 + j][sr] = (u16)v1v[j];
            }
        }
        __syncthreads();

        // QK^T : S_w[16 x 64]
        f32x4 sacc[4] = {};
#pragma unroll
        for (int n = 0; n < 4; n++) {
#pragma unroll
            for (int kc = 0; kc < 2; kc++) {
                short8_t kf = *(const short8_t*)&Kt[n * 16 + c][kc * 32 + g * 8];
                sacc[n] = __builtin_amdgcn_mfma_f32_16x16x32_bf16(qa[kc], kf, sacc[n], 0, 0, 0);
            }
        }

        // online softmax
        float p[4][4];
#pragma unroll
        for (int i = 0; i < 4; i++) {
            const int qg = q0 + g * 4 + i;
            float sv[4];
#pragma unroll
            for (int n = 0; n < 4; n++) {
                float x = sacc[n][i] * 0.125f;
                if (t == qt) {
                    int kg = t * 64 + n * 16 + c;
                    if (kg > qg) x = -1e30f;
                }
                sv[n] = x;
            }
            float mx = fmaxf(fmaxf(sv[0], sv[1]), fmaxf(sv[2], sv[3]));
#pragma unroll
            for (int msk = 1; msk < 16; msk <<= 1)
                mx = fmaxf(mx, __shfl_xor(mx, msk, 64));
            const float mnew = fmaxf(mrow[i], mx);
            const float corr = __expf(mrow[i] - mnew);
            float psum = 0.f;
#pragma unroll
            for (int n = 0; n < 4; n++) {
                float pv = __expf(sv[n] - mnew);
                p[n][i] = pv;
                psum += pv;
            }
#pragma unroll
            for (int msk = 1; msk < 16; msk <<= 1)
                psum += __shfl_xor(psum, msk, 64);
            lrow[i] = lrow[i] * corr + psum;
            mrow[i] = mnew;
#pragma unroll
            for (int n2 = 0; n2 < 4; n2++) o[n2][i] *= corr;
        }

        // P -> LDS (re-fragment for PV)
#pragma unroll
        for (int n = 0; n < 4; n++)
#pragma unroll
            for (int i = 0; i < 4; i++)
                Pb[w][g * 4 + i][n * 16 + c] = f2bf(p[n][i]);

        short8_t pa[2];
#pragma unroll
        for (int kc = 0; kc < 2; kc++)
            pa[kc] = *(const short8_t*)&Pb[w][c][kc * 32 + g * 8];

#pragma unroll
        for (int n2 = 0; n2 < 4; n2++) {
#pragma unroll
            for (int kc = 0; kc < 2; kc++) {
                short8_t vf = *(const short8_t*)&Vt[n2 * 16 + c][kc * 32 + g * 8];
                o[n2] = __builtin_amdgcn_mfma_f32_16x16x32_bf16(pa[kc], vf, o[n2], 0, 0, 0);
            }
        }
    }

    const int b_ = bh >> 4, h_ = bh & 15;
#pragma unroll
    for (int i = 0; i < 4; i++) {
        const int qg = q0 + g * 4 + i;
        const float inv = 1.0f / lrow[i];
        const size_t obase = ((size_t)b_ * SS + qg) * DD + h_ * 64;
#pragma unroll
        for (int n2 = 0; n2 < 4; n2++)
            attb[obase + n2 * 16 + c] = f2bf(o[n2][i] * inv);
    }
}

// ---------------------------------------------------------------------------
// Output projection: out = att @ Wo^T + bo (fp32 out)
// ---------------------------------------------------------------------------
__global__ __launch_bounds__(256) void out_gemm(
    const u16* __restrict__ A, const float* __restrict__ W,
    const float* __restrict__ bias, float* __restrict__ out)
{
    __shared__ u16 As[128][40];
    __shared__ u16 Bs[128][40];

    const int tid = threadIdx.x;
    const int lane = tid & 63;
    const int w  = tid >> 6;
    const int wr = w >> 1, wc = w & 1;
    const int g  = lane >> 4, c = lane & 15;

    const int m0 = blockIdx.x * 128;
    const int n0 = blockIdx.y * 128;

    f32x4 acc[4][4] = {};

    const int sr = tid >> 1;
    const int sc = (tid & 1) * 16;

    const u16*   ap = A + (size_t)(m0 + sr) * DD + sc;
    const float* bp = W + (size_t)(n0 + sr) * DD + sc;

    for (int k0 = 0; k0 < DD; k0 += 32) {
        short8_t wa0 = *(const short8_t*)(ap + k0);
        short8_t wa1 = *(const short8_t*)(ap + k0 + 8);
        f32x4 b4[4];
#pragma unroll
        for (int i = 0; i < 4; i++) b4[i] = *(const f32x4*)(bp + k0 + i * 4);
        short8_t wb0, wb1;
#pragma unroll
        for (int j = 0; j < 8; j++) {
            wb0[j] = (short)f2bf(b4[j >> 2][j & 3]);
            wb1[j] = (short)f2bf(b4[2 + (j >> 2)][j & 3]);
        }
        __syncthreads();
        *(short8_t*)&As[sr][sc]     = wa0;
        *(short8_t*)&As[sr][sc + 8] = wa1;
        *(short8_t*)&Bs[sr][sc]     = wb0;
        *(short8_t*)&Bs[sr][sc + 8] = wb1;
        __syncthreads();

        short8_t af[4], bf_[4];
#pragma unroll
        for (int m = 0; m < 4; m++) af[m]  = *(const short8_t*)&As[wr * 64 + m * 16 + c][g * 8];
#pragma unroll
        for (int n = 0; n < 4; n++) bf_[n] = *(const short8_t*)&Bs[wc * 64 + n * 16 + c][g * 8];
#pragma unroll
        for (int m = 0; m < 4; m++)
#pragma unroll
            for (int n = 0; n < 4; n++)
                acc[m][n] = __builtin_amdgcn_mfma_f32_16x16x32_bf16(af[m], bf_[n], acc[m][n], 0, 0, 0);
    }

#pragma unroll
    for (int m = 0; m < 4; m++)
#pragma unroll
        for (int n = 0; n < 4; n++) {
            const int gn = n0 + wc * 64 + n * 16 + c;
            const float bv_ = bias[gn];
#pragma unroll
            for (int i = 0; i < 4; i++) {
                const int gm = m0 + wr * 64 + m * 16 + g * 4 + i;
                out[(size_t)gm * DD + gn] = acc[m][n][i] + bv_;
            }
        }
}

// ---------------------------------------------------------------------------
extern "C" void kernel_launch(void* const* d_in, const int* in_sizes, int n_in,
                              void* d_out, int out_size, void* d_ws, size_t ws_size,
                              hipStream_t stream) {
    const float* query = (const float*)d_in[0];
    const float* key_  = (const float*)d_in[1];
    const float* value = (const float*)d_in[2];
    // d_in[3] = mask (causal, static) -- implemented analytically
    const float* Wq = (const float*)d_in[4];
    const float* bq = (const float*)d_in[5];
    const float* Wk = (const float*)d_in[6];
    const float* bk = (const float*)d_in[7];
    const float* Wv = (const float*)d_in[8];
    const float* bv = (const float*)d_in[9];
    const float* Wo = (const float*)d_in[10];
    const float* bo = (const float*)d_in[11];
    float* out = (float*)d_out;

    u16* ws = (u16*)d_ws;
    const size_t N = (size_t)BB * SS * DD;   // 8388608 elements
    u16* qb   = ws;
    u16* kb   = ws + N;
    u16* vb   = ws + 2 * N;
    u16* attb = ws + 3 * N;

    dim3 blk(256);
    dim3 g1(64, 8, 3);
    qkv_gemm<<<g1, blk, 0, stream>>>(query, key_, value, Wq, Wk, Wv, bq, bk, bv, qb, kb, vb);
    dim3 g2(32, 64);
    attn_kernel<<<g2, blk, 0, stream>>>(qb, kb, vb, attb);
    dim3 g3(64, 8);
    out_gemm<<<g3, blk, 0, stream>>>(attb, Wo, bo, out);
}

// Round 2
// 437.836 us; speedup vs baseline: 1.3516x; 1.3516x over previous
//
#include <hip/hip_runtime.h>
#include <hip/hip_bf16.h>
#include <stdint.h>

#define BB 4
#define SS 2048
#define DD 1024
#define HH 16
#define DHH 64

typedef __attribute__((ext_vector_type(8))) short short8_t;
typedef __attribute__((ext_vector_type(4))) short short4_t;
typedef __attribute__((ext_vector_type(4))) float f32x4;
typedef unsigned short u16;

static __device__ __forceinline__ u16 f2bf(float x) {
    uint32_t u = __float_as_uint(x);
    u += 0x7fffu + ((u >> 16) & 1u);
    return (u16)(u >> 16);
}

// ---------------------------------------------------------------------------
// fp32 -> bf16 converters (batched)
// ---------------------------------------------------------------------------
__global__ __launch_bounds__(256) void convert_x3(
    const float* __restrict__ a, const float* __restrict__ b, const float* __restrict__ c,
    u16* __restrict__ oa, u16* __restrict__ ob, u16* __restrict__ oc)
{
    const float* s; u16* d;
    if (blockIdx.z == 0)      { s = a; d = oa; }
    else if (blockIdx.z == 1) { s = b; d = ob; }
    else                      { s = c; d = oc; }
    size_t i = ((size_t)blockIdx.x * 256 + threadIdx.x) * 8;
    f32x4 v0 = *(const f32x4*)(s + i);
    f32x4 v1 = *(const f32x4*)(s + i + 4);
    short8_t o;
#pragma unroll
    for (int j = 0; j < 4; j++) { o[j] = (short)f2bf(v0[j]); o[4 + j] = (short)f2bf(v1[j]); }
    *(short8_t*)(d + i) = o;
}

__global__ __launch_bounds__(256) void convert_w4(
    const float* __restrict__ a, const float* __restrict__ b,
    const float* __restrict__ c, const float* __restrict__ dd_,
    u16* __restrict__ oa, u16* __restrict__ ob, u16* __restrict__ oc, u16* __restrict__ od)
{
    const float* s; u16* d;
    if (blockIdx.z == 0)      { s = a;   d = oa; }
    else if (blockIdx.z == 1) { s = b;   d = ob; }
    else if (blockIdx.z == 2) { s = c;   d = oc; }
    else                      { s = dd_; d = od; }
    size_t i = ((size_t)blockIdx.x * 256 + threadIdx.x) * 8;
    f32x4 v0 = *(const f32x4*)(s + i);
    f32x4 v1 = *(const f32x4*)(s + i + 4);
    short8_t o;
#pragma unroll
    for (int j = 0; j < 4; j++) { o[j] = (short)f2bf(v0[j]); o[4 + j] = (short)f2bf(v1[j]); }
    *(short8_t*)(d + i) = o;
}

// ---------------------------------------------------------------------------
// bf16 GEMM: out = A @ B^T + bias.  128x128 tile, BK=32, 4 waves.
// OMODE 0: u16 out in [B,H,S,DH];  1: u16 out in [B,H,DH,S] (V^T);  2: f32 [M,N]
// ---------------------------------------------------------------------------
template<int OMODE>
__global__ __launch_bounds__(256) void gemm_bf16(
    const u16* __restrict__ A, const u16* __restrict__ B,
    const float* __restrict__ bias, void* __restrict__ outp)
{
    __shared__ u16 As[128][40];
    __shared__ u16 Bs[128][40];

    const int tid = threadIdx.x;
    const int lane = tid & 63;
    const int w  = tid >> 6;
    const int wr = w >> 1, wc = w & 1;
    const int g  = lane >> 4, c = lane & 15;

    const int m0 = blockIdx.x * 128;
    const int n0 = blockIdx.y * 128;

    f32x4 acc[4][4] = {};

    const int sr = tid >> 1;
    const int sc = (tid & 1) * 16;

    const u16* ap = A + (size_t)(m0 + sr) * DD + sc;
    const u16* bp = B + (size_t)(n0 + sr) * DD + sc;

    for (int k0 = 0; k0 < DD; k0 += 32) {
        short8_t a0 = *(const short8_t*)(ap + k0);
        short8_t a1 = *(const short8_t*)(ap + k0 + 8);
        short8_t b0 = *(const short8_t*)(bp + k0);
        short8_t b1 = *(const short8_t*)(bp + k0 + 8);
        __syncthreads();
        *(short8_t*)&As[sr][sc]     = a0;
        *(short8_t*)&As[sr][sc + 8] = a1;
        *(short8_t*)&Bs[sr][sc]     = b0;
        *(short8_t*)&Bs[sr][sc + 8] = b1;
        __syncthreads();

        short8_t af[4], bfr[4];
#pragma unroll
        for (int m = 0; m < 4; m++) af[m]  = *(const short8_t*)&As[wr * 64 + m * 16 + c][g * 8];
#pragma unroll
        for (int n = 0; n < 4; n++) bfr[n] = *(const short8_t*)&Bs[wc * 64 + n * 16 + c][g * 8];
#pragma unroll
        for (int m = 0; m < 4; m++)
#pragma unroll
            for (int n = 0; n < 4; n++)
                acc[m][n] = __builtin_amdgcn_mfma_f32_16x16x32_bf16(af[m], bfr[n], acc[m][n], 0, 0, 0);
    }

    if (OMODE == 0) {
        u16* out = (u16*)outp;
#pragma unroll
        for (int m = 0; m < 4; m++)
#pragma unroll
            for (int n = 0; n < 4; n++) {
                const int gn = n0 + wc * 64 + n * 16 + c;
                const int h = gn >> 6, dh = gn & 63;
                const float bv_ = bias[gn];
#pragma unroll
                for (int i = 0; i < 4; i++) {
                    const int gm = m0 + wr * 64 + m * 16 + g * 4 + i;
                    const int b = gm >> 11, s = gm & (SS - 1);
                    out[(((size_t)(b * HH + h)) * SS + s) * DHH + dh] = f2bf(acc[m][n][i] + bv_);
                }
            }
    } else if (OMODE == 1) {
        u16* out = (u16*)outp;
#pragma unroll
        for (int m = 0; m < 4; m++)
#pragma unroll
            for (int n = 0; n < 4; n++) {
                const int gn = n0 + wc * 64 + n * 16 + c;
                const int h = gn >> 6, dh = gn & 63;
                const float bv_ = bias[gn];
                const int gm0 = m0 + wr * 64 + m * 16 + g * 4;
                const int b = gm0 >> 11, s = gm0 & (SS - 1);
                short4_t pk;
#pragma unroll
                for (int i = 0; i < 4; i++) pk[i] = (short)f2bf(acc[m][n][i] + bv_);
                *(short4_t*)&out[(((size_t)(b * HH + h)) * DHH + dh) * SS + s] = pk;
            }
    } else {
        float* out = (float*)outp;
#pragma unroll
        for (int m = 0; m < 4; m++)
#pragma unroll
            for (int n = 0; n < 4; n++) {
                const int gn = n0 + wc * 64 + n * 16 + c;
                const float bv_ = bias[gn];
#pragma unroll
                for (int i = 0; i < 4; i++) {
                    const int gm = m0 + wr * 64 + m * 16 + g * 4 + i;
                    out[(size_t)gm * DD + gn] = acc[m][n][i] + bv_;
                }
            }
    }
}

// ---------------------------------------------------------------------------
// attn v2: QBLK=128 (4 waves x 32 rows), KVB=64, no-max softmax with deferred
// l-reduction, XOR-swizzled K/V LDS, V consumed pre-transposed [B,H,DH,S].
// ---------------------------------------------------------------------------
__global__ __launch_bounds__(256) void attn_v2(
    const u16* __restrict__ qb, const u16* __restrict__ kb,
    const u16* __restrict__ vtb, u16* __restrict__ attb)
{
    __shared__ u16 Kt[64 * 64];
    __shared__ u16 Vt[64 * 64];
    __shared__ u16 Pb[4][32 * 64];

    const int tid = threadIdx.x;
    const int lane = tid & 63;
    const int w = tid >> 6;
    const int g = lane >> 4, c = lane & 15;
    const int qt = 15 - blockIdx.x;        // heavy tiles first
    const int bh = blockIdx.y;
    const size_t base = (size_t)bh * SS * DHH;   // same for [B,H,S,DH] and [B,H,DH,S]
    const int qw = qt * 128 + w * 32;

    short8_t qa[2][2];
#pragma unroll
    for (int fr = 0; fr < 2; fr++)
#pragma unroll
        for (int kc = 0; kc < 2; kc++)
            qa[fr][kc] = *(const short8_t*)(qb + base + (size_t)(qw + fr * 16 + c) * DHH + kc * 32 + g * 8);

    f32x4 o[2][4] = {};
    float lp[2][4] = {};

    const int NT = 2 * qt + 2;
    const int sr = tid >> 2;
    const int s4 = (tid & 3) * 16;
    const int swz = (sr & 7) << 3;
    const u16* kpb = kb  + base + (size_t)sr * DHH + s4;
    const u16* vpb = vtb + base + (size_t)sr * SS + s4;

    for (int t = 0; t < NT; ++t) {
        short8_t k0 = *(const short8_t*)(kpb + (size_t)t * 64 * DHH);
        short8_t k1 = *(const short8_t*)(kpb + (size_t)t * 64 * DHH + 8);
        short8_t v0 = *(const short8_t*)(vpb + t * 64);
        short8_t v1 = *(const short8_t*)(vpb + t * 64 + 8);
        __syncthreads();
        *(short8_t*)&Kt[sr * 64 + (s4 ^ swz)]       = k0;
        *(short8_t*)&Kt[sr * 64 + ((s4 + 8) ^ swz)] = k1;
        *(short8_t*)&Vt[sr * 64 + (s4 ^ swz)]       = v0;
        *(short8_t*)&Vt[sr * 64 + ((s4 + 8) ^ swz)] = v1;
        __syncthreads();

#pragma unroll
        for (int fr = 0; fr < 2; fr++) {
            const int qfr = qw + fr * 16;
            if (t * 64 > qfr + 15) continue;     // tile fully masked for this frag

            f32x4 sacc[4] = {};
#pragma unroll
            for (int n = 0; n < 4; n++) {
                const int row = n * 16 + c;
                const int rsw = (row & 7) << 3;
#pragma unroll
                for (int kc = 0; kc < 2; kc++) {
                    short8_t kf = *(const short8_t*)&Kt[row * 64 + ((kc * 32 + g * 8) ^ rsw)];
                    sacc[n] = __builtin_amdgcn_mfma_f32_16x16x32_bf16(qa[fr][kc], kf, sacc[n], 0, 0, 0);
                }
            }

            const bool diag = (t * 64 + 63 > qfr);
            float p[4][4];
#pragma unroll
            for (int i = 0; i < 4; i++) {
                const int qg2 = qfr + g * 4 + i;
#pragma unroll
                for (int n = 0; n < 4; n++) {
                    float pv = __expf(sacc[n][i] * 0.125f);
                    if (diag && (t * 64 + n * 16 + c > qg2)) pv = 0.f;
                    p[n][i] = pv;
                    lp[fr][i] += pv;
                }
            }

#pragma unroll
            for (int i = 0; i < 4; i++) {
                const int prow = fr * 16 + g * 4 + i;
                const int psw = (prow & 7) << 3;
#pragma unroll
                for (int n = 0; n < 4; n++)
                    Pb[w][prow * 64 + ((n * 16 + c) ^ psw)] = f2bf(p[n][i]);
            }

            short8_t pa[2];
            {
                const int prow = fr * 16 + c;
                const int psw = (prow & 7) << 3;
                pa[0] = *(const short8_t*)&Pb[w][prow * 64 + ((g * 8) ^ psw)];
                pa[1] = *(const short8_t*)&Pb[w][prow * 64 + ((32 + g * 8) ^ psw)];
            }
#pragma unroll
            for (int n2 = 0; n2 < 4; n2++) {
                const int vrow = n2 * 16 + c;
                const int vsw = (vrow & 7) << 3;
#pragma unroll
                for (int kc = 0; kc < 2; kc++) {
                    short8_t vf = *(const short8_t*)&Vt[vrow * 64 + ((kc * 32 + g * 8) ^ vsw)];
                    o[fr][n2] = __builtin_amdgcn_mfma_f32_16x16x32_bf16(pa[kc], vf, o[fr][n2], 0, 0, 0);
                }
            }
        }
    }

    const int b_ = bh >> 4, h_ = bh & 15;
#pragma unroll
    for (int fr = 0; fr < 2; fr++)
#pragma unroll
        for (int i = 0; i < 4; i++) {
            float l = lp[fr][i];
            l += __shfl_xor(l, 1, 64);
            l += __shfl_xor(l, 2, 64);
            l += __shfl_xor(l, 4, 64);
            l += __shfl_xor(l, 8, 64);
            const float inv = 1.0f / l;
            const int qg = qw + fr * 16 + g * 4 + i;
            const size_t obase = ((size_t)b_ * SS + qg) * DD + h_ * DHH;
#pragma unroll
            for (int n2 = 0; n2 < 4; n2++)
                attb[obase + n2 * 16 + c] = f2bf(o[fr][n2][i] * inv);
        }
}

// ===========================================================================
// v1 fallback kernels (verified round-1 pipeline), used if ws_size is small
// ===========================================================================
__global__ __launch_bounds__(256) void qkv_gemm_v1(
    const float* __restrict__ Xq, const float* __restrict__ Xk, const float* __restrict__ Xv,
    const float* __restrict__ Wq, const float* __restrict__ Wk, const float* __restrict__ Wv,
    const float* __restrict__ bq, const float* __restrict__ bk, const float* __restrict__ bv,
    u16* __restrict__ oq, u16* __restrict__ ok, u16* __restrict__ ov)
{
    const float* X; const float* W; const float* bias; u16* out;
    if (blockIdx.z == 0)      { X = Xq; W = Wq; bias = bq; out = oq; }
    else if (blockIdx.z == 1) { X = Xk; W = Wk; bias = bk; out = ok; }
    else                      { X = Xv; W = Wv; bias = bv; out = ov; }

    __shared__ u16 As[128][40];
    __shared__ u16 Bs[128][40];

    const int tid = threadIdx.x;
    const int lane = tid & 63;
    const int w  = tid >> 6;
    const int wr = w >> 1, wc = w & 1;
    const int g  = lane >> 4, c = lane & 15;
    const int m0 = blockIdx.x * 128;
    const int n0 = blockIdx.y * 128;
    f32x4 acc[4][4] = {};
    const int sr = tid >> 1;
    const int sc = (tid & 1) * 16;
    const float* ap = X + (size_t)(m0 + sr) * DD + sc;
    const float* bp = W + (size_t)(n0 + sr) * DD + sc;

    for (int k0 = 0; k0 < DD; k0 += 32) {
        f32x4 a4[4], b4[4];
#pragma unroll
        for (int i = 0; i < 4; i++) a4[i] = *(const f32x4*)(ap + k0 + i * 4);
#pragma unroll
        for (int i = 0; i < 4; i++) b4[i] = *(const f32x4*)(bp + k0 + i * 4);
        short8_t wa0, wa1, wb0, wb1;
#pragma unroll
        for (int j = 0; j < 8; j++) {
            wa0[j] = (short)f2bf(a4[j >> 2][j & 3]);
            wa1[j] = (short)f2bf(a4[2 + (j >> 2)][j & 3]);
            wb0[j] = (short)f2bf(b4[j >> 2][j & 3]);
            wb1[j] = (short)f2bf(b4[2 + (j >> 2)][j & 3]);
        }
        __syncthreads();
        *(short8_t*)&As[sr][sc]     = wa0;
        *(short8_t*)&As[sr][sc + 8] = wa1;
        *(short8_t*)&Bs[sr][sc]     = wb0;
        *(short8_t*)&Bs[sr][sc + 8] = wb1;
        __syncthreads();
        short8_t af[4], bf_[4];
#pragma unroll
        for (int m = 0; m < 4; m++) af[m]  = *(const short8_t*)&As[wr * 64 + m * 16 + c][g * 8];
#pragma unroll
        for (int n = 0; n < 4; n++) bf_[n] = *(const short8_t*)&Bs[wc * 64 + n * 16 + c][g * 8];
#pragma unroll
        for (int m = 0; m < 4; m++)
#pragma unroll
            for (int n = 0; n < 4; n++)
                acc[m][n] = __builtin_amdgcn_mfma_f32_16x16x32_bf16(af[m], bf_[n], acc[m][n], 0, 0, 0);
    }
#pragma unroll
    for (int m = 0; m < 4; m++)
#pragma unroll
        for (int n = 0; n < 4; n++) {
            const int gn = n0 + wc * 64 + n * 16 + c;
            const int h = gn >> 6, dh = gn & 63;
            const float bv_ = bias[gn];
#pragma unroll
            for (int i = 0; i < 4; i++) {
                const int gm = m0 + wr * 64 + m * 16 + g * 4 + i;
                const int b = gm >> 11, s = gm & (SS - 1);
                out[(((size_t)(b * HH + h)) * SS + s) * DHH + dh] = f2bf(acc[m][n][i] + bv_);
            }
        }
}

__global__ __launch_bounds__(256) void attn_v1(
    const u16* __restrict__ qb, const u16* __restrict__ kb,
    const u16* __restrict__ vb, u16* __restrict__ attb)
{
    __shared__ u16 Kt[64][72];
    __shared__ u16 Vt[64][72];
    __shared__ u16 Pb[4][16][72];

    const int tid = threadIdx.x;
    const int lane = tid & 63;
    const int w = tid >> 6;
    const int qt = blockIdx.x;
    const int bh = blockIdx.y;
    const size_t base = (size_t)bh * SS * DHH;
    const int g = lane >> 4;
    const int c = lane & 15;
    const int q0 = qt * 64 + w * 16;

    short8_t qa[2];
#pragma unroll
    for (int kc = 0; kc < 2; kc++)
        qa[kc] = *(const short8_t*)(qb + base + (size_t)(q0 + c) * DHH + kc * 32 + g * 8);

    f32x4 o[4] = {};
    float mrow[4], lrow[4];
#pragma unroll
    for (int i = 0; i < 4; i++) { mrow[i] = -1e30f; lrow[i] = 0.f; }

    const int sr  = tid >> 2;
    const int scc = (tid & 3) * 16;

    for (int t = 0; t <= qt; t++) {
        __syncthreads();
        {
            const u16* kp = kb + base + (size_t)(t * 64 + sr) * DHH + scc;
            short8_t k0v = *(const short8_t*)kp;
            short8_t k1v = *(const short8_t*)(kp + 8);
            *(short8_t*)&Kt[sr][scc]     = k0v;
            *(short8_t*)&Kt[sr][scc + 8] = k1v;
            const u16* vp = vb + base + (size_t)(t * 64 + sr) * DHH + scc;
            short8_t v0v = *(const short8_t*)vp;
            short8_t v1v = *(const short8_t*)(vp + 8);
#pragma unroll
            for (int j = 0; j < 8; j++) {
                Vt[scc + j][sr]     = (u16)v0v[j];
                Vt[scc + 8 + j][sr] = (u16)v1v[j];
            }
        }
        __syncthreads();

        f32x4 sacc[4] = {};
#pragma unroll
        for (int n = 0; n < 4; n++) {
#pragma unroll
            for (int kc = 0; kc < 2; kc++) {
                short8_t kf = *(const short8_t*)&Kt[n * 16 + c][kc * 32 + g * 8];
                sacc[n] = __builtin_amdgcn_mfma_f32_16x16x32_bf16(qa[kc], kf, sacc[n], 0, 0, 0);
            }
        }

        float p[4][4];
#pragma unroll
        for (int i = 0; i < 4; i++) {
            const int qg = q0 + g * 4 + i;
            float sv[4];
#pragma unroll
            for (int n = 0; n < 4; n++) {
                float x = sacc[n][i] * 0.125f;
                if (t == qt) {
                    int kg = t * 64 + n * 16 + c;
                    if (kg > qg) x = -1e30f;
                }
                sv[n] = x;
            }
            float mx = fmaxf(fmaxf(sv[0], sv[1]), fmaxf(sv[2], sv[3]));
#pragma unroll
            for (int msk = 1; msk < 16; msk <<= 1)
                mx = fmaxf(mx, __shfl_xor(mx, msk, 64));
            const float mnew = fmaxf(mrow[i], mx);
            const float corr = __expf(mrow[i] - mnew);
            float psum = 0.f;
#pragma unroll
            for (int n = 0; n < 4; n++) {
                float pv = __expf(sv[n] - mnew);
                p[n][i] = pv;
                psum += pv;
            }
#pragma unroll
            for (int msk = 1; msk < 16; msk <<= 1)
                psum += __shfl_xor(psum, msk, 64);
            lrow[i] = lrow[i] * corr + psum;
            mrow[i] = mnew;
#pragma unroll
            for (int n2 = 0; n2 < 4; n2++) o[n2][i] *= corr;
        }

#pragma unroll
        for (int n = 0; n < 4; n++)
#pragma unroll
            for (int i = 0; i < 4; i++)
                Pb[w][g * 4 + i][n * 16 + c] = f2bf(p[n][i]);

        short8_t pa[2];
#pragma unroll
        for (int kc = 0; kc < 2; kc++)
            pa[kc] = *(const short8_t*)&Pb[w][c][kc * 32 + g * 8];

#pragma unroll
        for (int n2 = 0; n2 < 4; n2++) {
#pragma unroll
            for (int kc = 0; kc < 2; kc++) {
                short8_t vf = *(const short8_t*)&Vt[n2 * 16 + c][kc * 32 + g * 8];
                o[n2] = __builtin_amdgcn_mfma_f32_16x16x32_bf16(pa[kc], vf, o[n2], 0, 0, 0);
            }
        }
    }

    const int b_ = bh >> 4, h_ = bh & 15;
#pragma unroll
    for (int i = 0; i < 4; i++) {
        const int qg = q0 + g * 4 + i;
        const float inv = 1.0f / lrow[i];
        const size_t obase = ((size_t)b_ * SS + qg) * DD + h_ * 64;
#pragma unroll
        for (int n2 = 0; n2 < 4; n2++)
            attb[obase + n2 * 16 + c] = f2bf(o[n2][i] * inv);
    }
}

__global__ __launch_bounds__(256) void out_gemm_v1(
    const u16* __restrict__ A, const float* __restrict__ W,
    const float* __restrict__ bias, float* __restrict__ out)
{
    __shared__ u16 As[128][40];
    __shared__ u16 Bs[128][40];

    const int tid = threadIdx.x;
    const int lane = tid & 63;
    const int w  = tid >> 6;
    const int wr = w >> 1, wc = w & 1;
    const int g  = lane >> 4, c = lane & 15;
    const int m0 = blockIdx.x * 128;
    const int n0 = blockIdx.y * 128;
    f32x4 acc[4][4] = {};
    const int sr = tid >> 1;
    const int sc = (tid & 1) * 16;
    const u16*   ap = A + (size_t)(m0 + sr) * DD + sc;
    const float* bp = W + (size_t)(n0 + sr) * DD + sc;

    for (int k0 = 0; k0 < DD; k0 += 32) {
        short8_t wa0 = *(const short8_t*)(ap + k0);
        short8_t wa1 = *(const short8_t*)(ap + k0 + 8);
        f32x4 b4[4];
#pragma unroll
        for (int i = 0; i < 4; i++) b4[i] = *(const f32x4*)(bp + k0 + i * 4);
        short8_t wb0, wb1;
#pragma unroll
        for (int j = 0; j < 8; j++) {
            wb0[j] = (short)f2bf(b4[j >> 2][j & 3]);
            wb1[j] = (short)f2bf(b4[2 + (j >> 2)][j & 3]);
        }
        __syncthreads();
        *(short8_t*)&As[sr][sc]     = wa0;
        *(short8_t*)&As[sr][sc + 8] = wa1;
        *(short8_t*)&Bs[sr][sc]     = wb0;
        *(short8_t*)&Bs[sr][sc + 8] = wb1;
        __syncthreads();
        short8_t af[4], bf_[4];
#pragma unroll
        for (int m = 0; m < 4; m++) af[m]  = *(const short8_t*)&As[wr * 64 + m * 16 + c][g * 8];
#pragma unroll
        for (int n = 0; n < 4; n++) bf_[n] = *(const short8_t*)&Bs[wc * 64 + n * 16 + c][g * 8];
#pragma unroll
        for (int m = 0; m < 4; m++)
#pragma unroll
            for (int n = 0; n < 4; n++)
                acc[m][n] = __builtin_amdgcn_mfma_f32_16x16x32_bf16(af[m], bf_[n], acc[m][n], 0, 0, 0);
    }

#pragma unroll
    for (int m = 0; m < 4; m++)
#pragma unroll
        for (int n = 0; n < 4; n++) {
            const int gn = n0 + wc * 64 + n * 16 + c;
            const float bv_ = bias[gn];
#pragma unroll
            for (int i = 0; i < 4; i++) {
                const int gm = m0 + wr * 64 + m * 16 + g * 4 + i;
                out[(size_t)gm * DD + gn] = acc[m][n][i] + bv_;
            }
        }
}

// ---------------------------------------------------------------------------
extern "C" void kernel_launch(void* const* d_in, const int* in_sizes, int n_in,
                              void* d_out, int out_size, void* d_ws, size_t ws_size,
                              hipStream_t stream) {
    const float* query = (const float*)d_in[0];
    const float* key_  = (const float*)d_in[1];
    const float* value = (const float*)d_in[2];
    const float* Wq = (const float*)d_in[4];
    const float* bq = (const float*)d_in[5];
    const float* Wk = (const float*)d_in[6];
    const float* bk = (const float*)d_in[7];
    const float* Wv = (const float*)d_in[8];
    const float* bv = (const float*)d_in[9];
    const float* Wo = (const float*)d_in[10];
    const float* bo = (const float*)d_in[11];
    float* out = (float*)d_out;

    u16* ws = (u16*)d_ws;
    const size_t N  = (size_t)BB * SS * DD;   // 8388608
    const size_t WN = (size_t)DD * DD;        // 1048576

    const size_t need = (4 * N + 4 * WN) * sizeof(u16);
    dim3 blk(256);

    if (ws_size >= need) {
        // slot map: s0 = xq->attb, s1 = xk->vtb, s2 = xv->qb, s3 = kb, s4 = w[4]
        u16* s0 = ws;
        u16* s1 = ws + N;
        u16* s2 = ws + 2 * N;
        u16* s3 = ws + 3 * N;
        u16* w4 = ws + 4 * N;

        convert_x3<<<dim3(4096, 1, 3), blk, 0, stream>>>(query, key_, value, s0, s1, s2);
        convert_w4<<<dim3(512, 1, 4), blk, 0, stream>>>(Wq, Wk, Wv, Wo,
                                                        w4, w4 + WN, w4 + 2 * WN, w4 + 3 * WN);
        gemm_bf16<0><<<dim3(64, 8), blk, 0, stream>>>(s1, w4 + WN,     bk, s3);  // K  -> kb  (s3)
        gemm_bf16<1><<<dim3(64, 8), blk, 0, stream>>>(s2, w4 + 2 * WN, bv, s1);  // V^T-> vtb (s1, xk dead)
        gemm_bf16<0><<<dim3(64, 8), blk, 0, stream>>>(s0, w4,          bq, s2);  // Q  -> qb  (s2, xv dead)
        attn_v2<<<dim3(16, 64), blk, 0, stream>>>(s2, s3, s1, s0);               // -> attb (s0, xq dead)
        gemm_bf16<2><<<dim3(64, 8), blk, 0, stream>>>(s0, w4 + 3 * WN, bo, out);
    } else {
        u16* qb   = ws;
        u16* kb   = ws + N;
        u16* vb   = ws + 2 * N;
        u16* attb = ws + 3 * N;
        qkv_gemm_v1<<<dim3(64, 8, 3), blk, 0, stream>>>(query, key_, value, Wq, Wk, Wv,
                                                        bq, bk, bv, qb, kb, vb);
        attn_v1<<<dim3(32, 64), blk, 0, stream>>>(qb, kb, vb, attb);
        out_gemm_v1<<<dim3(64, 8), blk, 0, stream>>>(attb, Wo, bo, out);
    }
}

// Round 3
// 410.912 us; speedup vs baseline: 1.4401x; 1.0655x over previous
//
#include <hip/hip_runtime.h>
#include <hip/hip_bf16.h>
#include <stdint.h>

#define BB 4
#define SS 2048
#define DD 1024
#define HH 16
#define DHH 64

typedef __attribute__((ext_vector_type(8))) short short8_t;
typedef __attribute__((ext_vector_type(4))) short short4_t;
typedef __attribute__((ext_vector_type(4))) float f32x4;
typedef unsigned short u16;

static __device__ __forceinline__ u16 f2bf(float x) {
    uint32_t u = __float_as_uint(x);
    u += 0x7fffu + ((u >> 16) & 1u);
    return (u16)(u >> 16);
}

// async global->LDS, 16B per lane; LDS dest = wave-uniform base + lane*16
static __device__ __forceinline__ void gload16(const void* g, void* l) {
    __builtin_amdgcn_global_load_lds((const __attribute__((address_space(1))) void*)g,
                                     (__attribute__((address_space(3))) void*)l, 16, 0, 0);
}

// ---------------------------------------------------------------------------
// fp32 -> bf16 converters
// ---------------------------------------------------------------------------
__global__ __launch_bounds__(256) void convert_x3(
    const float* __restrict__ a, const float* __restrict__ b, const float* __restrict__ c,
    u16* __restrict__ oa, u16* __restrict__ ob, u16* __restrict__ oc)
{
    const float* s; u16* d;
    if (blockIdx.z == 0)      { s = a; d = oa; }
    else if (blockIdx.z == 1) { s = b; d = ob; }
    else                      { s = c; d = oc; }
    size_t i = ((size_t)blockIdx.x * 256 + threadIdx.x) * 8;
    f32x4 v0 = *(const f32x4*)(s + i);
    f32x4 v1 = *(const f32x4*)(s + i + 4);
    short8_t o;
#pragma unroll
    for (int j = 0; j < 4; j++) { o[j] = (short)f2bf(v0[j]); o[4 + j] = (short)f2bf(v1[j]); }
    *(short8_t*)(d + i) = o;
}

__global__ __launch_bounds__(256) void convert_w4(
    const float* __restrict__ a, const float* __restrict__ b,
    const float* __restrict__ c, const float* __restrict__ dd_,
    u16* __restrict__ oa, u16* __restrict__ ob, u16* __restrict__ oc, u16* __restrict__ od)
{
    const float* s; u16* d;
    if (blockIdx.z == 0)      { s = a;   d = oa; }
    else if (blockIdx.z == 1) { s = b;   d = ob; }
    else if (blockIdx.z == 2) { s = c;   d = oc; }
    else                      { s = dd_; d = od; }
    size_t i = ((size_t)blockIdx.x * 256 + threadIdx.x) * 8;
    f32x4 v0 = *(const f32x4*)(s + i);
    f32x4 v1 = *(const f32x4*)(s + i + 4);
    short8_t o;
#pragma unroll
    for (int j = 0; j < 4; j++) { o[j] = (short)f2bf(v0[j]); o[4 + j] = (short)f2bf(v1[j]); }
    *(short8_t*)(d + i) = o;
}

// ---------------------------------------------------------------------------
// GEMM v3 (m97 structure): out = A @ B^T + bias. 128x128 tile, BK=64,
// global_load_lds width-16 staging with pre-swizzled source (involution:
// LDS[r][slot] holds global k-slot (slot ^ (r&7)); ds_read applies same XOR).
// OMODE 0: u16 [B,H,S,DH]; 1: u16 [B,H,DH,S] (V^T); 2: f32 [M,N]
// ---------------------------------------------------------------------------
template<int OMODE>
__global__ __launch_bounds__(256) void gemm_v3(
    const u16* __restrict__ A, const u16* __restrict__ B,
    const float* __restrict__ bias, void* __restrict__ outp)
{
    __shared__ u16 As[128 * 64];
    __shared__ u16 Bs[128 * 64];

    const int tid = threadIdx.x;
    const int lane = tid & 63;
    const int w  = tid >> 6;
    const int wr = w >> 1, wc = w & 1;
    const int g  = lane >> 4, c = lane & 15;
    const int cs7 = c & 7;

    const int m0 = blockIdx.x * 128;
    const int n0 = blockIdx.y * 128;

    f32x4 acc[4][4] = {};

    // staging geometry: wave w, issue j covers rows w*32+j*8 .. +7 (8 rows x 128B)
    // lane covers row w*32+j*8 + (lane>>3), 16B slot (lane&7)
    const int srow  = w * 32 + (lane >> 3);          // j=0 row; +8 per j; (row&7) static
    const int sslot = (lane & 7) ^ (srow & 7);       // pre-swizzled global k-slot
    const u16* aSrc = A + (size_t)(m0 + srow) * DD + sslot * 8;
    const u16* bSrc = B + (size_t)(n0 + srow) * DD + sslot * 8;

    for (int ks = 0; ks < 16; ks++) {
        __syncthreads();
#pragma unroll
        for (int j = 0; j < 4; j++) {
            gload16(aSrc + (size_t)j * 8 * DD + ks * 64, &As[(w * 32 + j * 8) * 64]);
            gload16(bSrc + (size_t)j * 8 * DD + ks * 64, &Bs[(w * 32 + j * 8) * 64]);
        }
        __syncthreads();

#pragma unroll
        for (int kc = 0; kc < 2; kc++) {
            const int rdoff = ((kc * 4 + g) ^ cs7) * 8;
            short8_t af[4], bfr[4];
#pragma unroll
            for (int m = 0; m < 4; m++)
                af[m] = *(const short8_t*)&As[(wr * 64 + m * 16 + c) * 64 + rdoff];
#pragma unroll
            for (int n = 0; n < 4; n++)
                bfr[n] = *(const short8_t*)&Bs[(wc * 64 + n * 16 + c) * 64 + rdoff];
#pragma unroll
            for (int m = 0; m < 4; m++)
#pragma unroll
                for (int n = 0; n < 4; n++)
                    acc[m][n] = __builtin_amdgcn_mfma_f32_16x16x32_bf16(af[m], bfr[n], acc[m][n], 0, 0, 0);
        }
    }

    if (OMODE == 0) {
        u16* out = (u16*)outp;
#pragma unroll
        for (int m = 0; m < 4; m++)
#pragma unroll
            for (int n = 0; n < 4; n++) {
                const int gn = n0 + wc * 64 + n * 16 + c;
                const int h = gn >> 6, dh = gn & 63;
                const float bv_ = bias[gn];
#pragma unroll
                for (int i = 0; i < 4; i++) {
                    const int gm = m0 + wr * 64 + m * 16 + g * 4 + i;
                    const int b = gm >> 11, s = gm & (SS - 1);
                    out[(((size_t)(b * HH + h)) * SS + s) * DHH + dh] = f2bf(acc[m][n][i] + bv_);
                }
            }
    } else if (OMODE == 1) {
        u16* out = (u16*)outp;
#pragma unroll
        for (int m = 0; m < 4; m++)
#pragma unroll
            for (int n = 0; n < 4; n++) {
                const int gn = n0 + wc * 64 + n * 16 + c;
                const int h = gn >> 6, dh = gn & 63;
                const float bv_ = bias[gn];
                const int gm0 = m0 + wr * 64 + m * 16 + g * 4;
                const int b = gm0 >> 11, s = gm0 & (SS - 1);
                short4_t pk;
#pragma unroll
                for (int i = 0; i < 4; i++) pk[i] = (short)f2bf(acc[m][n][i] + bv_);
                *(short4_t*)&out[(((size_t)(b * HH + h)) * DHH + dh) * SS + s] = pk;
            }
    } else {
        float* out = (float*)outp;
#pragma unroll
        for (int m = 0; m < 4; m++)
#pragma unroll
            for (int n = 0; n < 4; n++) {
                const int gn = n0 + wc * 64 + n * 16 + c;
                const float bv_ = bias[gn];
#pragma unroll
                for (int i = 0; i < 4; i++) {
                    const int gm = m0 + wr * 64 + m * 16 + g * 4 + i;
                    out[(size_t)gm * DD + gn] = acc[m][n][i] + bv_;
                }
            }
    }
}

// ---------------------------------------------------------------------------
// attn v3: swapped QK^T (lane owns q-row = c), packed-u32 P transpose through
// swizzled per-wave LDS, shared K/V frags across both q-frags, async K/V
// prefetch into regs, deferred l-reduction, no-max softmax (logits bounded).
// ---------------------------------------------------------------------------
__global__ __launch_bounds__(256) void attn_v3(
    const u16* __restrict__ qb, const u16* __restrict__ kb,
    const u16* __restrict__ vtb, u16* __restrict__ attb)
{
    __shared__ u16 Kt[64 * 64];
    __shared__ u16 Vt[64 * 64];
    __shared__ u16 Pb[4][32 * 64];

    const int tid = threadIdx.x;
    const int lane = tid & 63;
    const int w = tid >> 6;
    const int g = lane >> 4, c = lane & 15;
    const int cs7 = c & 7;
    const int qt = 15 - blockIdx.x;          // heavy tiles first
    const int bh = blockIdx.y;
    const size_t base = (size_t)bh * SS * DHH;
    const int qw = qt * 128 + w * 32;

    short8_t qa[2][2];
#pragma unroll
    for (int fr = 0; fr < 2; fr++)
#pragma unroll
        for (int kc = 0; kc < 2; kc++)
            qa[fr][kc] = *(const short8_t*)(qb + base + (size_t)(qw + fr * 16 + c) * DHH + kc * 32 + g * 8);

    f32x4 o[2][4] = {};
    float lp[2] = {0.f, 0.f};

    const int NT = 2 * qt + 2;
    const int sr = tid >> 2;
    const int s4 = (tid & 3) * 16;
    const int swz = (sr & 7) << 3;
    const u16* kpb = kb  + base + (size_t)sr * DHH + s4;
    const u16* vpb = vtb + base + (size_t)sr * SS + s4;

    // prefetch tile 0
    short8_t kr0 = *(const short8_t*)(kpb);
    short8_t kr1 = *(const short8_t*)(kpb + 8);
    short8_t vr0 = *(const short8_t*)(vpb);
    short8_t vr1 = *(const short8_t*)(vpb + 8);

    for (int t = 0; t < NT; ++t) {
        __syncthreads();
        *(short8_t*)&Kt[sr * 64 + (s4 ^ swz)]       = kr0;
        *(short8_t*)&Kt[sr * 64 + ((s4 + 8) ^ swz)] = kr1;
        *(short8_t*)&Vt[sr * 64 + (s4 ^ swz)]       = vr0;
        *(short8_t*)&Vt[sr * 64 + ((s4 + 8) ^ swz)] = vr1;
        __syncthreads();

        if (t + 1 < NT) {   // async prefetch next tile; lands during compute below
            kr0 = *(const short8_t*)(kpb + (size_t)(t + 1) * 64 * DHH);
            kr1 = *(const short8_t*)(kpb + (size_t)(t + 1) * 64 * DHH + 8);
            vr0 = *(const short8_t*)(vpb + (t + 1) * 64);
            vr1 = *(const short8_t*)(vpb + (t + 1) * 64 + 8);
        }

        const int k0g = t * 64;
        const bool act0 = (k0g <= qw + 15);
        const bool act1 = (k0g <= qw + 31);

        // QK^T swapped: sacc[fr][n] holds S^T[key = k0g+16n+4g+i][q = qfr+c]
        f32x4 sacc[2][4] = {};
#pragma unroll
        for (int n = 0; n < 4; n++) {
            const int krow = n * 16 + c;
            const int ksw = (krow & 7) << 3;
#pragma unroll
            for (int kc = 0; kc < 2; kc++) {
                short8_t kf = *(const short8_t*)&Kt[krow * 64 + ((kc * 32 + g * 8) ^ ksw)];
                if (act0) sacc[0][n] = __builtin_amdgcn_mfma_f32_16x16x32_bf16(kf, qa[0][kc], sacc[0][n], 0, 0, 0);
                if (act1) sacc[1][n] = __builtin_amdgcn_mfma_f32_16x16x32_bf16(kf, qa[1][kc], sacc[1][n], 0, 0, 0);
            }
        }

        const bool diag = (k0g + 63 > qw);
#pragma unroll
        for (int fr = 0; fr < 2; fr++) {
            if (fr == 0 ? !act0 : !act1) continue;
            const int qq = qw + fr * 16 + c;
            float e[4][4];
            float ls = 0.f;
#pragma unroll
            for (int n = 0; n < 4; n++) {
                const int kbse = k0g + n * 16 + 4 * g;
#pragma unroll
                for (int i = 0; i < 4; i++) {
                    float pv = exp2f(sacc[fr][n][i] * 0.18033688f);   // 0.125 * log2(e)
                    if (diag && (kbse + i > qq)) pv = 0.f;
                    e[n][i] = pv;
                    ls += pv;
                }
            }
            lp[fr] += ls;
            // P transpose: store u32 pairs so lane q-row data becomes A-frag rows
            const int prow = (fr * 16 + c) * 64;
#pragma unroll
            for (int n = 0; n < 4; n++)
#pragma unroll
                for (int hi = 0; hi < 2; hi++) {
                    uint32_t pk = (__float_as_uint(e[n][2 * hi]) >> 16) |
                                  (__float_as_uint(e[n][2 * hi + 1]) & 0xFFFF0000u);
                    *(uint32_t*)&Pb[w][prow + (((2 * n + (g >> 1)) ^ cs7) * 8 + 4 * (g & 1) + 2 * hi)] = pk;
                }
        }

        short8_t pa[2][2];
        if (act0) {
            const int prow = c * 64;
            pa[0][0] = *(const short8_t*)&Pb[w][prow + ((g ^ cs7) * 8)];
            pa[0][1] = *(const short8_t*)&Pb[w][prow + (((4 + g) ^ cs7) * 8)];
        }
        if (act1) {
            const int prow = (16 + c) * 64;
            pa[1][0] = *(const short8_t*)&Pb[w][prow + ((g ^ cs7) * 8)];
            pa[1][1] = *(const short8_t*)&Pb[w][prow + (((4 + g) ^ cs7) * 8)];
        }

#pragma unroll
        for (int n2 = 0; n2 < 4; n2++) {
            const int vrow = n2 * 16 + c;
            const int vsw = (vrow & 7) << 3;
#pragma unroll
            for (int kc = 0; kc < 2; kc++) {
                short8_t vf = *(const short8_t*)&Vt[vrow * 64 + ((kc * 32 + g * 8) ^ vsw)];
                if (act0) o[0][n2] = __builtin_amdgcn_mfma_f32_16x16x32_bf16(pa[0][kc], vf, o[0][n2], 0, 0, 0);
                if (act1) o[1][n2] = __builtin_amdgcn_mfma_f32_16x16x32_bf16(pa[1][kc], vf, o[1][n2], 0, 0, 0);
            }
        }
    }

    const int b_ = bh >> 4, h_ = bh & 15;
#pragma unroll
    for (int fr = 0; fr < 2; fr++) {
        float l = lp[fr];
        l += __shfl_xor(l, 16, 64);
        l += __shfl_xor(l, 32, 64);     // all lanes: l for q = qw + fr*16 + c
#pragma unroll
        for (int i = 0; i < 4; i++) {
            const float li = __shfl(l, g * 4 + i, 16);
            const float inv = 1.0f / li;
            const int qg = qw + fr * 16 + g * 4 + i;
            const size_t obase = ((size_t)b_ * SS + qg) * DD + h_ * DHH;
#pragma unroll
            for (int n2 = 0; n2 < 4; n2++)
                attb[obase + n2 * 16 + c] = f2bf(o[fr][n2][i] * inv);
        }
    }
}

// ---------------------------------------------------------------------------
extern "C" void kernel_launch(void* const* d_in, const int* in_sizes, int n_in,
                              void* d_out, int out_size, void* d_ws, size_t ws_size,
                              hipStream_t stream) {
    const float* query = (const float*)d_in[0];
    const float* key_  = (const float*)d_in[1];
    const float* value = (const float*)d_in[2];
    // d_in[3] = mask (causal, static) -- implemented analytically
    const float* Wq = (const float*)d_in[4];
    const float* bq = (const float*)d_in[5];
    const float* Wk = (const float*)d_in[6];
    const float* bk = (const float*)d_in[7];
    const float* Wv = (const float*)d_in[8];
    const float* bv = (const float*)d_in[9];
    const float* Wo = (const float*)d_in[10];
    const float* bo = (const float*)d_in[11];
    float* out = (float*)d_out;

    u16* ws = (u16*)d_ws;
    const size_t N  = (size_t)BB * SS * DD;   // 8388608
    const size_t WN = (size_t)DD * DD;        // 1048576

    // slot map: s0 = xq->attb, s1 = xk->vtb, s2 = xv->qb, s3 = kb, w4 = weights
    u16* s0 = ws;
    u16* s1 = ws + N;
    u16* s2 = ws + 2 * N;
    u16* s3 = ws + 3 * N;
    u16* w4 = ws + 4 * N;

    dim3 blk(256);
    convert_x3<<<dim3(4096, 1, 3), blk, 0, stream>>>(query, key_, value, s0, s1, s2);
    convert_w4<<<dim3(512, 1, 4), blk, 0, stream>>>(Wq, Wk, Wv, Wo,
                                                    w4, w4 + WN, w4 + 2 * WN, w4 + 3 * WN);
    gemm_v3<0><<<dim3(64, 8), blk, 0, stream>>>(s1, w4 + WN,     bk, s3);  // K   -> kb  (s3)
    gemm_v3<1><<<dim3(64, 8), blk, 0, stream>>>(s2, w4 + 2 * WN, bv, s1);  // V^T -> vtb (s1)
    gemm_v3<0><<<dim3(64, 8), blk, 0, stream>>>(s0, w4,          bq, s2);  // Q   -> qb  (s2)
    attn_v3<<<dim3(16, 64), blk, 0, stream>>>(s2, s3, s1, s0);             // -> attb (s0)
    gemm_v3<2><<<dim3(64, 8), blk, 0, stream>>>(s0, w4 + 3 * WN, bo, out);
}